// Round 3
// baseline (782.712 us; speedup 1.0000x reference)
//
#include <hip/hip_runtime.h>
#include <math.h>

#define N_NODES    100000
#define N_EDGES    3200000
#define NUM_GRAPHS 512
#define D_IN       7
#define D_H        16
#define SHIFT      7
#define BWIDTH     128                               // cols per bucket
#define NB         782                               // ceil(N_NODES / BWIDTH)
#define CHUNK      8192
#define NCHUNK     ((N_EDGES + CHUNK - 1) / CHUNK)   // 391

// ---- pass A: exact per-bucket edge counts (LDS-aggregated) ----
__global__ void bin_count_kernel(const int* __restrict__ col, int* __restrict__ bcnt) {
    __shared__ int lh[NB];
    for (int i = threadIdx.x; i < NB; i += blockDim.x) lh[i] = 0;
    __syncthreads();
    int tid = blockIdx.x * blockDim.x + threadIdx.x;
    int stride = gridDim.x * blockDim.x;
    for (int e = tid; e < N_EDGES; e += stride) atomicAdd(&lh[col[e] >> SHIFT], 1);
    __syncthreads();
    for (int i = threadIdx.x; i < NB; i += blockDim.x) {
        int c = lh[i];
        if (c) atomicAdd(&bcnt[i], c);
    }
}

// ---- pass B: exclusive scan -> bucket offsets + cursors (single block) ----
__global__ void scan_kernel(const int* __restrict__ bcnt, int* __restrict__ offs,
                            int* __restrict__ cur) {
    __shared__ int lds[1024];
    int tid = threadIdx.x;
    lds[tid] = (tid < NB) ? bcnt[tid] : 0;
    __syncthreads();
    for (int st = 1; st < 1024; st <<= 1) {
        int v = (tid >= st) ? lds[tid - st] : 0;
        __syncthreads();
        lds[tid] += v;
        __syncthreads();
    }
    if (tid < NB) {
        offs[tid + 1] = lds[tid];
        cur[tid] = (tid == 0) ? 0 : lds[tid - 1];
    }
    if (tid == 0) offs[0] = 0;
}

// ---- pass C: place edges into bucket-contiguous regions; one returning atomic
//      per (block,bucket), not per edge. packed word = (row<<7) | (col & 127) ----
__global__ void place_kernel(const int* __restrict__ row, const int* __restrict__ col,
                             int* __restrict__ cur, int* __restrict__ part) {
    __shared__ int lh[NB];   // local counts, then unused
    __shared__ int lb[NB];   // local base cursors
    int e0 = blockIdx.x * CHUNK;
    int e1 = e0 + CHUNK; if (e1 > N_EDGES) e1 = N_EDGES;
    for (int i = threadIdx.x; i < NB; i += blockDim.x) lh[i] = 0;
    __syncthreads();
    for (int e = e0 + threadIdx.x; e < e1; e += blockDim.x)
        atomicAdd(&lh[col[e] >> SHIFT], 1);
    __syncthreads();
    for (int i = threadIdx.x; i < NB; i += blockDim.x) {
        int c = lh[i];
        lb[i] = c ? atomicAdd(&cur[i], c) : 0;
    }
    __syncthreads();
    for (int e = e0 + threadIdx.x; e < e1; e += blockDim.x) {
        int cc = col[e];
        int b = cc >> SHIFT;
        int pos = atomicAdd(&lb[b], 1);               // LDS atomic
        part[pos] = (row[e] << SHIFT) | (cc & (BWIDTH - 1));
    }
}

// ---- per-bucket in-degree via LDS histogram ----
__global__ void bdeg_kernel(const int* __restrict__ part, const int* __restrict__ offs,
                            int* __restrict__ deg) {
    __shared__ int bins[BWIDTH];
    int b = blockIdx.x;
    if (threadIdx.x < BWIDTH) bins[threadIdx.x] = 0;
    __syncthreads();
    int o0 = offs[b], o1 = offs[b + 1];
    for (int j = o0 + threadIdx.x; j < o1; j += blockDim.x)
        atomicAdd(&bins[part[j] & (BWIDTH - 1)], 1);
    __syncthreads();
    if (threadIdx.x < BWIDTH) {
        int c = b * BWIDTH + threadIdx.x;
        if (c < N_NODES) deg[c] = bins[threadIdx.x];
    }
}

__global__ void dinv_kernel(const int* __restrict__ deg, float* __restrict__ dinv) {
    int v = blockIdx.x * blockDim.x + threadIdx.x;
    if (v < N_NODES) dinv[v] = rsqrtf((float)deg[v] + 1.0f);  // +1 self-loop
}

// s[v,:] = dinv[v] * (x[v,:] @ W1)
__global__ void xw1_kernel(const float* __restrict__ x, const float* __restrict__ W1,
                           const float* __restrict__ dinv, float* __restrict__ s) {
    int v = blockIdx.x * blockDim.x + threadIdx.x;
    if (v >= N_NODES) return;
    float xv[D_IN];
#pragma unroll
    for (int j = 0; j < D_IN; ++j) xv[j] = x[v * D_IN + j];
    float dv = dinv[v];
#pragma unroll
    for (int k = 0; k < D_H; ++k) {
        float a = 0.f;
#pragma unroll
        for (int j = 0; j < D_IN; ++j) a += xv[j] * W1[j * D_H + k];
        s[v * D_H + k] = a * dv;
    }
}

// s[v,:] = dinv[v] * (h[v,:] @ W2)
__global__ void hw2_kernel(const float* __restrict__ h, const float* __restrict__ W2,
                           const float* __restrict__ dinv, float* __restrict__ s) {
    int v = blockIdx.x * blockDim.x + threadIdx.x;
    if (v >= N_NODES) return;
    float hv[D_H];
#pragma unroll
    for (int j = 0; j < D_H; ++j) hv[j] = h[v * D_H + j];
    float dv = dinv[v];
#pragma unroll
    for (int k = 0; k < D_H; ++k) {
        float a = 0.f;
#pragma unroll
        for (int j = 0; j < D_H; ++j) a += hv[j] * W2[j * D_H + k];
        s[v * D_H + k] = a * dv;
    }
}

// ---- SpMM: one block per bucket, LDS accumulator, zero global atomics.
// hout[c,k] = relu(dinv[c]*(sum_r s[r,k] + s[c,k]) + bias[k]) for c in bucket ----
__global__ void spmm_kernel(const float* __restrict__ s, const int* __restrict__ part,
                            const int* __restrict__ offs, const float* __restrict__ dinv,
                            const float* __restrict__ bias, float* __restrict__ hout) {
    __shared__ float acc[BWIDTH * D_H];   // 8 KB
    int b = blockIdx.x;
    for (int i = threadIdx.x; i < BWIDTH * D_H; i += blockDim.x) acc[i] = 0.f;
    __syncthreads();
    int o0 = offs[b];
    int n = offs[b + 1] - o0;
    int wave = threadIdx.x >> 6, lane = threadIdx.x & 63;
    int sub = lane >> 4, k = lane & 15;
    int j = wave * 4 + sub;                // 16 edge-slots per iteration across block
    while (j + 16 < n) {                   // 2-deep unroll for latency hiding
        int e1 = part[o0 + j], e2 = part[o0 + j + 16];
        float v1 = s[(e1 >> SHIFT) * D_H + k];
        float v2 = s[(e2 >> SHIFT) * D_H + k];
        atomicAdd(&acc[(e1 & (BWIDTH - 1)) * D_H + k], v1);
        atomicAdd(&acc[(e2 & (BWIDTH - 1)) * D_H + k], v2);
        j += 32;
    }
    while (j < n) {
        int e = part[o0 + j];
        atomicAdd(&acc[(e & (BWIDTH - 1)) * D_H + k], s[(e >> SHIFT) * D_H + k]);
        j += 16;
    }
    __syncthreads();
    for (int i = threadIdx.x; i < BWIDTH * D_H; i += blockDim.x) {
        int cl = i >> 4, kk = i & 15;
        int c = b * BWIDTH + cl;
        if (c < N_NODES) {
            float o = dinv[c] * (acc[i] + s[c * D_H + kk]) + bias[kk];
            hout[c * D_H + kk] = fmaxf(o, 0.f);
        }
    }
}

// batch sorted: starts[g] = first node of graph g; starts[NUM_GRAPHS] = N
__global__ void starts_kernel(const int* __restrict__ batch, int* __restrict__ starts) {
    int v = blockIdx.x * blockDim.x + threadIdx.x;
    if (v >= N_NODES) return;
    int bv = batch[v];
    int prev = (v == 0) ? -1 : batch[v - 1];
    for (int g = prev + 1; g <= bv; ++g) starts[g] = v;
    if (v == N_NODES - 1) {
        for (int g = bv + 1; g <= NUM_GRAPHS; ++g) starts[g] = N_NODES;
    }
}

// one block per graph: mean-pool h rows then sigmoid(pool @ Wl + bl)
__global__ void pool_head_kernel(const float* __restrict__ h, const int* __restrict__ starts,
                                 const float* __restrict__ Wl, const float* __restrict__ bl,
                                 float* __restrict__ out) {
    int g = blockIdx.x;
    int v0 = starts[g], v1 = starts[g + 1];
    int k = threadIdx.x & 15;
    int vi = threadIdx.x >> 4;
    float acc = 0.f;
    for (int v = v0 + vi; v < v1; v += 16) acc += h[v * D_H + k];
    acc += __shfl_xor(acc, 16, 64);
    acc += __shfl_xor(acc, 32, 64);
    __shared__ float sm[4][D_H];
    int lane = threadIdx.x & 63;
    if (lane < 16) sm[threadIdx.x >> 6][k] = acc;
    __syncthreads();
    if (threadIdx.x < 16) {
        float tot = sm[0][k] + sm[1][k] + sm[2][k] + sm[3][k];
        float cntf = (float)(v1 - v0);
        tot /= fmaxf(cntf, 1.0f);
        float p = tot * Wl[k];
        p += __shfl_xor(p, 1, 64);
        p += __shfl_xor(p, 2, 64);
        p += __shfl_xor(p, 4, 64);
        p += __shfl_xor(p, 8, 64);
        if (k == 0) out[g] = 1.0f / (1.0f + expf(-(p + bl[0])));
    }
}

// ---------------- launch ----------------

extern "C" void kernel_launch(void* const* d_in, const int* in_sizes, int n_in,
                              void* d_out, int out_size, void* d_ws, size_t ws_size,
                              hipStream_t stream) {
    const float* x     = (const float*)d_in[0];
    const int*   ei    = (const int*)d_in[1];   // [2, E]: row then col
    const int*   batch = (const int*)d_in[2];
    const float* W1    = (const float*)d_in[3];
    const float* b1    = (const float*)d_in[4];
    const float* W2    = (const float*)d_in[5];
    const float* b2    = (const float*)d_in[6];
    const float* Wl    = (const float*)d_in[7];
    const float* bl    = (const float*)d_in[8];
    float* out = (float*)d_out;

    const int* row = ei;
    const int* col = ei + N_EDGES;

    // workspace layout (4-byte words), ~27.5 MB total
    char* wsb = (char*)d_ws;
    size_t o = 0;
    int*   part   = (int*)(wsb + o);   o += (size_t)N_EDGES * 4;     // 12.8 MB
    int*   bcnt   = (int*)(wsb + o);   o += 1024 * 4;
    int*   offs   = (int*)(wsb + o);   o += 1024 * 4;
    int*   cur    = (int*)(wsb + o);   o += 1024 * 4;
    int*   deg    = (int*)(wsb + o);   o += 100352 * 4;
    float* dinv   = (float*)(wsb + o); o += 100352 * 4;
    float* s      = (float*)(wsb + o); o += (size_t)N_NODES * D_H * 4;
    float* h      = (float*)(wsb + o); o += (size_t)N_NODES * D_H * 4;
    int*   starts = (int*)(wsb + o);   o += 1024 * 4;

    const int B = 256;
    const int NVB = (N_NODES + B - 1) / B;   // 391

    // ---- partition edges by col-bucket ----
    hipMemsetAsync(bcnt, 0, NB * sizeof(int), stream);
    bin_count_kernel<<<512, B, 0, stream>>>(col, bcnt);
    scan_kernel<<<1, 1024, 0, stream>>>(bcnt, offs, cur);
    place_kernel<<<NCHUNK, B, 0, stream>>>(row, col, cur, part);

    // ---- degrees + dinv ----
    bdeg_kernel<<<NB, B, 0, stream>>>(part, offs, deg);
    dinv_kernel<<<NVB, B, 0, stream>>>(deg, dinv);

    // ---- layer 1 ----
    xw1_kernel<<<NVB, B, 0, stream>>>(x, W1, dinv, s);
    spmm_kernel<<<NB, B, 0, stream>>>(s, part, offs, dinv, b1, h);

    // ---- layer 2 ----
    hw2_kernel<<<NVB, B, 0, stream>>>(h, W2, dinv, s);
    spmm_kernel<<<NB, B, 0, stream>>>(s, part, offs, dinv, b2, h);

    // ---- pool + head ----
    starts_kernel<<<NVB, B, 0, stream>>>(batch, starts);
    pool_head_kernel<<<NUM_GRAPHS, B, 0, stream>>>(h, starts, Wl, bl, out);
}

// Round 4
// 239.038 us; speedup vs baseline: 3.2744x; 3.2744x over previous
//
#include <hip/hip_runtime.h>
#include <math.h>

#define N_NODES    100000
#define N_EDGES    3200000
#define NUM_GRAPHS 512
#define D_IN       7
#define D_H        16
#define SHIFT      7
#define BWIDTH     128                               // cols per bucket
#define NB         782                               // ceil(N_NODES / BWIDTH)
#define CHUNK      8192
#define NCHUNK     ((N_EDGES + CHUNK - 1) / CHUNK)   // 391

// ---- pass A: exact per-bucket edge counts (LDS-aggregated) ----
__global__ void bin_count_kernel(const int* __restrict__ col, int* __restrict__ bcnt) {
    __shared__ int lh[NB];
    for (int i = threadIdx.x; i < NB; i += blockDim.x) lh[i] = 0;
    __syncthreads();
    int tid = blockIdx.x * blockDim.x + threadIdx.x;
    int stride = gridDim.x * blockDim.x;
    for (int e = tid; e < N_EDGES; e += stride) atomicAdd(&lh[col[e] >> SHIFT], 1);
    __syncthreads();
    for (int i = threadIdx.x; i < NB; i += blockDim.x) {
        int c = lh[i];
        if (c) atomicAdd(&bcnt[i], c);
    }
}

// ---- pass B: exclusive scan -> bucket offsets + cursors (single block) ----
__global__ void scan_kernel(const int* __restrict__ bcnt, int* __restrict__ offs,
                            int* __restrict__ cur) {
    __shared__ int lds[1024];
    int tid = threadIdx.x;
    lds[tid] = (tid < NB) ? bcnt[tid] : 0;
    __syncthreads();
    for (int st = 1; st < 1024; st <<= 1) {
        int v = (tid >= st) ? lds[tid - st] : 0;
        __syncthreads();
        lds[tid] += v;
        __syncthreads();
    }
    if (tid < NB) {
        offs[tid + 1] = lds[tid];
        cur[tid] = (tid == 0) ? 0 : lds[tid - 1];
    }
    if (tid == 0) offs[0] = 0;
}

// ---- pass C: place edges into bucket-contiguous regions; one returning atomic
//      per (block,bucket). packed word = (row<<7) | (col & 127) ----
__global__ void place_kernel(const int* __restrict__ row, const int* __restrict__ col,
                             int* __restrict__ cur, int* __restrict__ part) {
    __shared__ int lh[NB];
    __shared__ int lb[NB];
    int e0 = blockIdx.x * CHUNK;
    int e1 = e0 + CHUNK; if (e1 > N_EDGES) e1 = N_EDGES;
    for (int i = threadIdx.x; i < NB; i += blockDim.x) lh[i] = 0;
    __syncthreads();
    for (int e = e0 + threadIdx.x; e < e1; e += blockDim.x)
        atomicAdd(&lh[col[e] >> SHIFT], 1);
    __syncthreads();
    for (int i = threadIdx.x; i < NB; i += blockDim.x) {
        int c = lh[i];
        lb[i] = c ? atomicAdd(&cur[i], c) : 0;
    }
    __syncthreads();
    for (int e = e0 + threadIdx.x; e < e1; e += blockDim.x) {
        int cc = col[e];
        int b = cc >> SHIFT;
        int pos = atomicAdd(&lb[b], 1);               // LDS atomic
        part[pos] = (row[e] << SHIFT) | (cc & (BWIDTH - 1));
    }
}

// ---- pass D: per-bucket CSR build. LDS histogram -> scan -> reorder.
//      Also emits node_off, deg, dinv. Zero global atomics. ----
__global__ void csr_kernel(const int* __restrict__ part, const int* __restrict__ offs,
                           int* __restrict__ csr, int* __restrict__ node_off,
                           int* __restrict__ deg, float* __restrict__ dinv) {
    __shared__ int cnt[BWIDTH];
    __shared__ int scn[BWIDTH];
    __shared__ int cur[BWIDTH];
    int b = blockIdx.x;
    int o0 = offs[b], o1 = offs[b + 1];
    if (threadIdx.x < BWIDTH) cnt[threadIdx.x] = 0;
    __syncthreads();
    for (int j = o0 + threadIdx.x; j < o1; j += blockDim.x)
        atomicAdd(&cnt[part[j] & (BWIDTH - 1)], 1);
    __syncthreads();
    if (threadIdx.x < BWIDTH) scn[threadIdx.x] = cnt[threadIdx.x];
    __syncthreads();
    for (int st = 1; st < BWIDTH; st <<= 1) {
        int v = 0;
        if (threadIdx.x < BWIDTH && threadIdx.x >= st) v = scn[threadIdx.x - st];
        __syncthreads();
        if (threadIdx.x < BWIDTH) scn[threadIdx.x] += v;
        __syncthreads();
    }
    if (threadIdx.x < BWIDTH) {
        int excl = scn[threadIdx.x] - cnt[threadIdx.x];
        cur[threadIdx.x] = excl;
        int c = b * BWIDTH + threadIdx.x;
        if (c < N_NODES) {
            node_off[c] = o0 + excl;
            deg[c] = cnt[threadIdx.x];
            dinv[c] = rsqrtf((float)cnt[threadIdx.x] + 1.0f);   // +1 self-loop
        }
    }
    __syncthreads();
    for (int j = o0 + threadIdx.x; j < o1; j += blockDim.x) {
        int e = part[j];
        int l = e & (BWIDTH - 1);
        int pos = atomicAdd(&cur[l], 1);              // LDS atomic
        csr[o0 + pos] = e >> SHIFT;
    }
}

// s[v,:] = dinv[v] * (x[v,:] @ W1)
__global__ void xw1_kernel(const float* __restrict__ x, const float* __restrict__ W1,
                           const float* __restrict__ dinv, float* __restrict__ s) {
    int v = blockIdx.x * blockDim.x + threadIdx.x;
    if (v >= N_NODES) return;
    float xv[D_IN];
#pragma unroll
    for (int j = 0; j < D_IN; ++j) xv[j] = x[v * D_IN + j];
    float dv = dinv[v];
#pragma unroll
    for (int k = 0; k < D_H; ++k) {
        float a = 0.f;
#pragma unroll
        for (int j = 0; j < D_IN; ++j) a += xv[j] * W1[j * D_H + k];
        s[v * D_H + k] = a * dv;
    }
}

// s[v,:] = dinv[v] * (h[v,:] @ W2)
__global__ void hw2_kernel(const float* __restrict__ h, const float* __restrict__ W2,
                           const float* __restrict__ dinv, float* __restrict__ s) {
    int v = blockIdx.x * blockDim.x + threadIdx.x;
    if (v >= N_NODES) return;
    float hv[D_H];
#pragma unroll
    for (int j = 0; j < D_H; ++j) hv[j] = h[v * D_H + j];
    float dv = dinv[v];
#pragma unroll
    for (int k = 0; k < D_H; ++k) {
        float a = 0.f;
#pragma unroll
        for (int j = 0; j < D_H; ++j) a += hv[j] * W2[j * D_H + k];
        s[v * D_H + k] = a * dv;
    }
}

// pull-gather + finalize: one wave per node; 4 edge-slots x 16 features, 2-deep.
// h[v,k] = relu(dinv[v]*(sum_r s[r,k] + s[v,k]) + b[k])
__global__ void pull_kernel(const float* __restrict__ s, const int* __restrict__ csr,
                            const int* __restrict__ node_off, const int* __restrict__ deg,
                            const float* __restrict__ dinv, const float* __restrict__ b,
                            float* __restrict__ h) {
    int wave = threadIdx.x >> 6;            // 4 waves per block
    int v = blockIdx.x * 4 + wave;
    if (v >= N_NODES) return;
    int lane = threadIdx.x & 63;
    int sub = lane >> 4;                    // 0..3 edge-slot group
    int k   = lane & 15;                    // feature
    int d   = deg[v];
    int o0  = node_off[v];
    float acc = 0.f;
    int j = sub;
    for (; j + 4 < d; j += 8) {             // 2 lines in flight
        int r1 = csr[o0 + j];
        int r2 = csr[o0 + j + 4];
        float v1 = s[r1 * D_H + k];
        float v2 = s[r2 * D_H + k];
        acc += v1 + v2;
    }
    for (; j < d; j += 4) acc += s[csr[o0 + j] * D_H + k];
    acc += __shfl_xor(acc, 16, 64);
    acc += __shfl_xor(acc, 32, 64);
    if (sub == 0) {
        float o = dinv[v] * (acc + s[v * D_H + k]) + b[k];
        h[v * D_H + k] = fmaxf(o, 0.f);
    }
}

// batch sorted: starts[g] = first node of graph g; starts[NUM_GRAPHS] = N
__global__ void starts_kernel(const int* __restrict__ batch, int* __restrict__ starts) {
    int v = blockIdx.x * blockDim.x + threadIdx.x;
    if (v >= N_NODES) return;
    int bv = batch[v];
    int prev = (v == 0) ? -1 : batch[v - 1];
    for (int g = prev + 1; g <= bv; ++g) starts[g] = v;
    if (v == N_NODES - 1) {
        for (int g = bv + 1; g <= NUM_GRAPHS; ++g) starts[g] = N_NODES;
    }
}

// one block per graph: mean-pool h rows then sigmoid(pool @ Wl + bl)
__global__ void pool_head_kernel(const float* __restrict__ h, const int* __restrict__ starts,
                                 const float* __restrict__ Wl, const float* __restrict__ bl,
                                 float* __restrict__ out) {
    int g = blockIdx.x;
    int v0 = starts[g], v1 = starts[g + 1];
    int k = threadIdx.x & 15;
    int vi = threadIdx.x >> 4;
    float acc = 0.f;
    for (int v = v0 + vi; v < v1; v += 16) acc += h[v * D_H + k];
    acc += __shfl_xor(acc, 16, 64);
    acc += __shfl_xor(acc, 32, 64);
    __shared__ float sm[4][D_H];
    int lane = threadIdx.x & 63;
    if (lane < 16) sm[threadIdx.x >> 6][k] = acc;
    __syncthreads();
    if (threadIdx.x < 16) {
        float tot = sm[0][k] + sm[1][k] + sm[2][k] + sm[3][k];
        float cntf = (float)(v1 - v0);
        tot /= fmaxf(cntf, 1.0f);
        float p = tot * Wl[k];
        p += __shfl_xor(p, 1, 64);
        p += __shfl_xor(p, 2, 64);
        p += __shfl_xor(p, 4, 64);
        p += __shfl_xor(p, 8, 64);
        if (k == 0) out[g] = 1.0f / (1.0f + expf(-(p + bl[0])));
    }
}

// ---------------- launch ----------------

extern "C" void kernel_launch(void* const* d_in, const int* in_sizes, int n_in,
                              void* d_out, int out_size, void* d_ws, size_t ws_size,
                              hipStream_t stream) {
    const float* x     = (const float*)d_in[0];
    const int*   ei    = (const int*)d_in[1];   // [2, E]: row then col
    const int*   batch = (const int*)d_in[2];
    const float* W1    = (const float*)d_in[3];
    const float* b1    = (const float*)d_in[4];
    const float* W2    = (const float*)d_in[5];
    const float* b2    = (const float*)d_in[6];
    const float* Wl    = (const float*)d_in[7];
    const float* bl    = (const float*)d_in[8];
    float* out = (float*)d_out;

    const int* row = ei;
    const int* col = ei + N_EDGES;

    // workspace layout (4-byte words), ~40 MB total
    char* wsb = (char*)d_ws;
    size_t o = 0;
    int*   part     = (int*)(wsb + o);   o += (size_t)N_EDGES * 4;   // 12.8 MB
    int*   csr      = (int*)(wsb + o);   o += (size_t)N_EDGES * 4;   // 12.8 MB
    int*   bcnt     = (int*)(wsb + o);   o += 1024 * 4;
    int*   offs     = (int*)(wsb + o);   o += 1024 * 4;
    int*   cur      = (int*)(wsb + o);   o += 1024 * 4;
    int*   node_off = (int*)(wsb + o);   o += 100352 * 4;
    int*   deg      = (int*)(wsb + o);   o += 100352 * 4;
    float* dinv     = (float*)(wsb + o); o += 100352 * 4;
    float* s        = (float*)(wsb + o); o += (size_t)N_NODES * D_H * 4;
    float* h        = (float*)(wsb + o); o += (size_t)N_NODES * D_H * 4;
    int*   starts   = (int*)(wsb + o);   o += 1024 * 4;

    const int B = 256;
    const int NVB = (N_NODES + B - 1) / B;   // 391

    // ---- build bucket-partition then CSR (no per-edge global atomics) ----
    hipMemsetAsync(bcnt, 0, NB * sizeof(int), stream);
    bin_count_kernel<<<512, B, 0, stream>>>(col, bcnt);
    scan_kernel<<<1, 1024, 0, stream>>>(bcnt, offs, cur);
    place_kernel<<<NCHUNK, B, 0, stream>>>(row, col, cur, part);
    csr_kernel<<<NB, B, 0, stream>>>(part, offs, csr, node_off, deg, dinv);

    // ---- layer 1 ----
    xw1_kernel<<<NVB, B, 0, stream>>>(x, W1, dinv, s);
    pull_kernel<<<(N_NODES + 3) / 4, B, 0, stream>>>(s, csr, node_off, deg, dinv, b1, h);

    // ---- layer 2 ----
    hw2_kernel<<<NVB, B, 0, stream>>>(h, W2, dinv, s);
    pull_kernel<<<(N_NODES + 3) / 4, B, 0, stream>>>(s, csr, node_off, deg, dinv, b2, h);

    // ---- pool + head ----
    starts_kernel<<<NVB, B, 0, stream>>>(batch, starts);
    pool_head_kernel<<<NUM_GRAPHS, B, 0, stream>>>(h, starts, Wl, bl, out);
}